// Round 5
// baseline (600.800 us; speedup 1.0000x reference)
//
#include <hip/hip_runtime.h>
#include <hip/hip_bf16.h>
#include <stdint.h>

// ---------- types ----------
typedef __bf16 bf16x8 __attribute__((ext_vector_type(8)));
typedef float  f32x16 __attribute__((ext_vector_type(16)));
typedef unsigned short u16x8 __attribute__((ext_vector_type(8)));

#define HS    1024     // hidden size
#define FOURH 4096
#define SEQ   512
#define BATCH 64

#define BAR() asm volatile("s_barrier" ::: "memory")
#define VMW(n) asm volatile("s_waitcnt vmcnt(" #n ")" ::: "memory")

// manual round-to-nearest-even f32 -> bf16 bits
__device__ __forceinline__ unsigned short f2bf(float f) {
    unsigned u = __builtin_bit_cast(unsigned, f);
    u = (u + 0x7FFFu + ((u >> 16) & 1u)) >> 16;
    return (unsigned short)u;
}

__device__ __forceinline__ void gload_lds16(const void* g, void* l) {
    __builtin_amdgcn_global_load_lds(
        (const __attribute__((address_space(1))) void*)g,
        (__attribute__((address_space(3))) void*)l, 16, 0, 0);
}

// ---------- kernel 1: x (f32) -> Xb (bf16) ----------
__global__ __launch_bounds__(256) void convert_x(const float* __restrict__ x,
                                                 unsigned short* __restrict__ xb,
                                                 long n8) {
    long i = (long)blockIdx.x * blockDim.x + threadIdx.x;
    long stride = (long)gridDim.x * blockDim.x;
    for (; i < n8; i += stride) {
        const float4* p = (const float4*)(x + i * 8);
        float4 a = p[0], b = p[1];
        u16x8 o;
        o[0] = f2bf(a.x); o[1] = f2bf(a.y); o[2] = f2bf(a.z); o[3] = f2bf(a.w);
        o[4] = f2bf(b.x); o[5] = f2bf(b.y); o[6] = f2bf(b.z); o[7] = f2bf(b.w);
        *(u16x8*)(xb + i * 8) = o;
    }
}

// ---------- kernel 2: U [1024][4096] f32 -> Ut [4096][1024] bf16 ----------
__global__ __launch_bounds__(256) void transpose_u(const float* __restrict__ U,
                                                   unsigned short* __restrict__ Ut) {
    __shared__ float tile[32][33];
    int bx = blockIdx.x;            // 4096 blocks
    int tn = bx >> 5;               // n tile
    int tk = bx & 31;               // k tile
    int c = threadIdx.x & 31;
    int r = threadIdx.x >> 5;
#pragma unroll
    for (int i = 0; i < 4; ++i) {
        int k = tk * 32 + r + i * 8;
        tile[r + i * 8][c] = U[(size_t)k * FOURH + tn * 32 + c];
    }
    __syncthreads();
#pragma unroll
    for (int i = 0; i < 4; ++i) {
        int nl = r + i * 8;
        Ut[(size_t)(tn * 32 + nl) * HS + tk * 32 + c] = f2bf(tile[c][nl]);
    }
}

// ---------- kernel 3: 256x256 GEMM, 32x32x16 MFMA, BK=64 ring-2, 1 bar/tile --
// 8 waves (2M x 4N), per-wave 128x64 = 4x2 frags of 32x32. LDS: A subtiles
// packed [32 rows][16 k] as [octet][row] (contiguous 1KB per wave b128 read,
// conflict-free by construction; gload_lds lane-linear write = this layout).
__global__ __launch_bounds__(512, 2) void gemm_gates8(
    const unsigned short* __restrict__ Xb,   // [B*S][1024] bf16
    const unsigned short* __restrict__ Ut,   // [4096][1024] bf16
    const float* __restrict__ bias,          // [4096]
    _Float16* __restrict__ gates,            // [BATCH*chunk][4096] activated f16
    int lg2chunk, int s0) {
    __shared__ unsigned short LDSU[65536];   // 128KB: [slot]{A 32KB, B 32KB} x2

    // T1: XCD-aware block swizzle (nwg multiple of 8)
    int nwg = gridDim.x;
    int bid = blockIdx.x;
    int wg = (bid & 7) * (nwg >> 3) + (bid >> 3);
    int mt = wg >> 4;            // 16 n-tiles (4096/256)
    int nt = wg & 15;

    int tid = threadIdx.x;
    int w = tid >> 6, l = tid & 63;
    int wr = w >> 2, wc = w & 3;       // wave grid 2 (M) x 4 (N)
    int srow32 = l & 31, soct = l >> 5;

    const int m0 = mt * 256, n0 = nt * 256;
    const int cmask = (1 << lg2chunk) - 1;

    // staging global srcs: wave w stages A rows m0+w*32.., B rows n0+w*32..
    int arow = m0 + w * 32 + srow32;
    int ab = arow >> lg2chunk, asl = arow & cmask;
    const unsigned short* gA = Xb + (size_t)(ab * SEQ + s0 + asl) * HS + soct * 8;
    const unsigned short* gB = Ut + (size_t)(n0 + w * 32 + srow32) * HS + soct * 8;

    f32x16 acc[4][2];
#pragma unroll
    for (int mi = 0; mi < 4; ++mi)
#pragma unroll
        for (int ni = 0; ni < 2; ++ni) acc[mi][ni] = 0.f;

    // stage full K-tile t (A 4 subtile-ks + B 4) into slot t&1
    auto STAGE = [&](int t) {
        int slot = (t & 1) * 32768;
        int ko = t * 64;
#pragma unroll
        for (int ks = 0; ks < 4; ++ks) {
            gload_lds16(gA + ko + ks * 16, &LDSU[slot + (w * 4 + ks) * 512]);
            gload_lds16(gB + ko + ks * 16, &LDSU[slot + 16384 + (w * 4 + ks) * 512]);
        }
    };
    // frag reads: contiguous 1KB per instruction
    auto RDA = [&](int slot, int ks, bf16x8* d) {
#pragma unroll
        for (int mi = 0; mi < 4; ++mi)
            d[mi] = *(const bf16x8*)&LDSU[slot + ((wr * 4 + mi) * 4 + ks) * 512 +
                                          soct * 256 + srow32 * 8];
    };
    auto RDB = [&](int slot, int ks, bf16x8* d) {
#pragma unroll
        for (int ni = 0; ni < 2; ++ni)
            d[ni] = *(const bf16x8*)&LDSU[slot + 16384 + ((wc * 2 + ni) * 4 + ks) * 512 +
                                          soct * 256 + srow32 * 8];
    };
    auto MM = [&](bf16x8* a, bf16x8* b) {
        __builtin_amdgcn_s_setprio(1);
#pragma unroll
        for (int mi = 0; mi < 4; ++mi)
#pragma unroll
            for (int ni = 0; ni < 2; ++ni)
                acc[mi][ni] = __builtin_amdgcn_mfma_f32_32x32x16_bf16(
                    a[mi], b[ni], acc[mi][ni], 0, 0, 0);
        __builtin_amdgcn_s_setprio(0);
    };

    bf16x8 a0[4], a1[4], b0[2], b1[2];

    // prologue
    STAGE(0);
    VMW(0); BAR();
    RDA(0, 0, a0); RDB(0, 0, b0);

    for (int t = 0; t < 16; ++t) {
        int slot = (t & 1) * 32768;
        int nslot = slot ^ 32768;
        if (t < 15) STAGE(t + 1);            // 8 gloads, burst
        RDA(slot, 1, a1); RDB(slot, 1, b1);
        MM(a0, b0);                           // ks0
        RDA(slot, 2, a0); RDB(slot, 2, b0);
        MM(a1, b1);                           // ks1
        RDA(slot, 3, a1); RDB(slot, 3, b1);
        MM(a0, b0);                           // ks2
        if (t < 15) {
            VMW(0); BAR();                    // t+1 staged >=2 phases ago
            RDA(nslot, 0, a0); RDB(nslot, 0, b0);
        }
        MM(a1, b1);                           // ks3
    }

    // ---- epilogue: act -> f16 via LDS, then coalesced 16B global stores ----
    BAR();
    _Float16* T = (_Float16*)LDSU;   // [256][256] f16, col ^ ((row>>2&3)<<4)
#pragma unroll
    for (int ni = 0; ni < 2; ++ni) {
        int col = wc * 64 + ni * 32 + srow32;
        int gcol = n0 + col;
        bool is_g = ((gcol >> 10) == 2);
        float bv = bias[gcol];
#pragma unroll
        for (int mi = 0; mi < 4; ++mi) {
#pragma unroll
            for (int reg = 0; reg < 16; ++reg) {
                int row = wr * 128 + mi * 32 + (reg & 3) + 8 * (reg >> 2) + 4 * soct;
                float v = acc[mi][ni][reg] + bv;
                float e;
                if (is_g) e = 1.f - 2.f / (1.f + __expf(2.f * v));   // tanh
                else      e = 1.f / (1.f + __expf(-v));              // sigmoid
                T[row * 256 + (col ^ (((row >> 2) & 3) << 4))] = (_Float16)e;
            }
        }
    }
    BAR();
#pragma unroll
    for (int p = 0; p < 16; ++p) {
        int q = p * 512 + tid;           // 16B-slot id, 0..8191
        int row = q >> 5, s = q & 31;
        int cs = (s * 8) ^ (((row >> 2) & 3) << 4);
        uint4 val = *(const uint4*)(T + row * 256 + cs);
        *(uint4*)(gates + (size_t)(m0 + row) * FOURH + n0 + s * 8) = val;
    }
}

// ---------- kernel 4: recurrence, burst-8 prefetch, one thread per (b,h) ------
__global__ __launch_bounds__(256) void lstm_recur(
    const _Float16* __restrict__ gates,  // [64*chunk][4096] activated f16
    float* __restrict__ out,             // d_out base (f32)
    float* __restrict__ cstate,          // [65536]
    int chunk, int s0) {
    int t = blockIdx.x * 256 + threadIdx.x;  // 0..65535
    int b = t >> 10, h = t & 1023;
    float c = (s0 == 0) ? 0.f : cstate[t];
    const _Float16* gp = gates + (size_t)b * chunk * FOURH + h;
    float* op = out + (size_t)(b * SEQ + s0) * HS + h;
    float hv = 0.f;
    for (int sl = 0; sl < chunk; sl += 8) {
        float iv[8], fv[8], gv[8], ov[8];
#pragma unroll
        for (int u = 0; u < 8; ++u) {
            const _Float16* q = gp + (size_t)(sl + u) * FOURH;
            iv[u] = (float)q[0];
            fv[u] = (float)q[1024];
            gv[u] = (float)q[2048];
            ov[u] = (float)q[3072];
        }
#pragma unroll
        for (int u = 0; u < 8; ++u) {
            c = fv[u] * c + iv[u] * gv[u];
            float th = 1.f - 2.f / (1.f + __expf(2.f * c));
            hv = ov[u] * th;
            op[(size_t)(sl + u) * HS] = hv;
        }
    }
    cstate[t] = c;
    if (s0 + chunk == SEQ) {
        out[(size_t)BATCH * SEQ * HS + t] = hv;                      // h_T
        out[(size_t)BATCH * SEQ * HS + BATCH * HS + t] = c;          // c_T
    }
}

// ---------- launcher ----------
extern "C" void kernel_launch(void* const* d_in, const int* in_sizes, int n_in,
                              void* d_out, int out_size, void* d_ws, size_t ws_size,
                              hipStream_t stream) {
    const float* x    = (const float*)d_in[0];
    const float* U    = (const float*)d_in[1];
    const float* bias = (const float*)d_in[2];
    float* out = (float*)d_out;
    char*  ws  = (char*)d_ws;

    // ws layout
    unsigned short* Xb = (unsigned short*)ws;                   // 64MB  bf16 x
    unsigned short* Ut = (unsigned short*)(ws + 67108864);      // 8MB   bf16 U^T
    float* cstate      = (float*)(ws + 75497472);               // 256KB
    _Float16* gates    = (_Float16*)(ws + 75759616);            // chunk*0.5MB
    const size_t fixed = 75759616;

    int chunk = 512;
    while (chunk > 4 && fixed + (size_t)BATCH * chunk * FOURH * 2 > ws_size)
        chunk >>= 1;
    int lg2 = 31 - __builtin_clz(chunk);

    convert_x<<<2048, 256, 0, stream>>>(x, Xb, (long)BATCH * SEQ * HS / 8);
    transpose_u<<<4096, 256, 0, stream>>>(U, Ut);

    for (int s0 = 0; s0 < SEQ; s0 += chunk) {
        int mtiles = (BATCH * chunk) / 256;
        gemm_gates8<<<mtiles * 16, 512, 0, stream>>>(Xb, Ut, bias, gates, lg2, s0);
        lstm_recur<<<256, 256, 0, stream>>>(gates, out, cstate, chunk, s0);
    }
}

// Round 6
// 458.542 us; speedup vs baseline: 1.3102x; 1.3102x over previous
//
#include <hip/hip_runtime.h>
#include <hip/hip_bf16.h>
#include <stdint.h>

// ---------- types ----------
typedef __bf16 bf16x8 __attribute__((ext_vector_type(8)));
typedef float  f32x4  __attribute__((ext_vector_type(4)));
typedef unsigned short u16x8 __attribute__((ext_vector_type(8)));

#define HS    1024     // hidden size
#define FOURH 4096
#define SEQ   512
#define BATCH 64

#define BAR()  asm volatile("s_barrier" ::: "memory")
#define VMW(n) asm volatile("s_waitcnt vmcnt(" #n ")" ::: "memory")
#define LGKM0() asm volatile("s_waitcnt lgkmcnt(0)" ::: "memory")

// manual round-to-nearest-even f32 -> bf16 bits
__device__ __forceinline__ unsigned short f2bf(float f) {
    unsigned u = __builtin_bit_cast(unsigned, f);
    u = (u + 0x7FFFu + ((u >> 16) & 1u)) >> 16;
    return (unsigned short)u;
}

__device__ __forceinline__ void gload_lds16(const void* g, void* l) {
    __builtin_amdgcn_global_load_lds(
        (const __attribute__((address_space(1))) void*)g,
        (__attribute__((address_space(3))) void*)l, 16, 0, 0);
}

// ---------- kernel 1: x (f32) -> Xb (bf16) ----------
__global__ __launch_bounds__(256) void convert_x(const float* __restrict__ x,
                                                 unsigned short* __restrict__ xb,
                                                 long n8) {
    long i = (long)blockIdx.x * blockDim.x + threadIdx.x;
    long stride = (long)gridDim.x * blockDim.x;
    for (; i < n8; i += stride) {
        const float4* p = (const float4*)(x + i * 8);
        float4 a = p[0], b = p[1];
        u16x8 o;
        o[0] = f2bf(a.x); o[1] = f2bf(a.y); o[2] = f2bf(a.z); o[3] = f2bf(a.w);
        o[4] = f2bf(b.x); o[5] = f2bf(b.y); o[6] = f2bf(b.z); o[7] = f2bf(b.w);
        *(u16x8*)(xb + i * 8) = o;
    }
}

// ---------- kernel 2: U [1024][4096] f32 -> Ut [4096][1024] bf16 ----------
__global__ __launch_bounds__(256) void transpose_u(const float* __restrict__ U,
                                                   unsigned short* __restrict__ Ut) {
    __shared__ float tile[32][33];
    int bx = blockIdx.x;            // 4096 blocks
    int tn = bx >> 5;               // n tile
    int tk = bx & 31;               // k tile
    int c = threadIdx.x & 31;
    int r = threadIdx.x >> 5;
#pragma unroll
    for (int i = 0; i < 4; ++i) {
        int k = tk * 32 + r + i * 8;
        tile[r + i * 8][c] = U[(size_t)k * FOURH + tn * 32 + c];
    }
    __syncthreads();
#pragma unroll
    for (int i = 0; i < 4; ++i) {
        int nl = r + i * 8;
        Ut[(size_t)(tn * 32 + nl) * HS + tk * 32 + c] = f2bf(tile[c][nl]);
    }
}

// ---------- kernel 3: 256x256, BK=64, 4-quadrant-phase GEMM (m201 port) ------
// 8 waves (2M x 4N). Per tile: ph1 Q(0,0), ph2 Q(0,1), ph3 Q(1,1), ph4 Q(1,0).
// Stage t+1 quarters {A02, B01, B23, A13} at ph1..4. VMW(4)+BAR at ph2 end,
// VMW(2)+BAR at ph4 end (tile boundary). Never drains in main loop.
__global__ __launch_bounds__(512, 2) void gemm_gates8(
    const unsigned short* __restrict__ Xb,   // [B*S][1024] bf16
    const unsigned short* __restrict__ Ut,   // [4096][1024] bf16
    const float* __restrict__ bias,          // [4096]
    _Float16* __restrict__ gates,            // [BATCH*chunk][4096] activated f16
    int lg2chunk, int s0) {
    __shared__ unsigned short LDSU[65536];   // 128KB: buf(t&1)*32768; A@0, B@+16384

    // T1: XCD-aware block swizzle (nwg multiple of 8)
    int nwg = gridDim.x;
    int bid = blockIdx.x;
    int wg = (bid & 7) * (nwg >> 3) + (bid >> 3);
    int mt = wg >> 4;            // 16 n-tiles (4096/256)
    int nt = wg & 15;

    int tid = threadIdx.x;
    int w = tid >> 6, l = tid & 63;
    int wr = w >> 2, wc = w & 3;       // wave grid 2 (M) x 4 (N)
    int lr = l & 15, lg = l >> 4;

    const int m0 = mt * 256, n0 = nt * 256;
    const int cmask = (1 << lg2chunk) - 1;

    // ds_read offset within a 16x32 subtile (ushort units), st_16x32 swizzle
    const int rdo = lr * 32 + ((lg * 8) ^ ((lr & 8) << 1));

    // staging lane geometry: lane covers row l>>2 of its subtile, k-octet (l&3)
    const int srow = l >> 2;
    const int skin = ((l & 3) * 8) ^ (((l >> 5) & 1) << 4);

    // per-quarter global source pointers (quarter q = 64 rows; wave w covers
    // subtile rs = q*4 + (w>>1), kc = w&1)
    const unsigned short* pAq[4];
    const unsigned short* pBq[4];
#pragma unroll
    for (int q = 0; q < 4; ++q) {
        int rowg = q * 64 + (w >> 1) * 16 + srow;
        int mrow = m0 + rowg;
        int b = mrow >> lg2chunk, sl2 = mrow & cmask;
        pAq[q] = Xb + (size_t)(b * SEQ + s0 + sl2) * HS + (w & 1) * 32 + skin;
        pBq[q] = Ut + (size_t)(n0 + rowg) * HS + (w & 1) * 32 + skin;
    }
    const int dsub = (w >> 1) * 2 + (w & 1);   // subtile slot within quarter

    f32x4 acc[8][4];
#pragma unroll
    for (int mi = 0; mi < 8; ++mi)
#pragma unroll
        for (int ni = 0; ni < 4; ++ni) acc[mi][ni] = 0.f;

#define SA(T, Q) gload_lds16(pAq[Q] + (T) * 64, \
        &LDSU[(((T) & 1) << 15) + ((Q) * 8 + dsub) * 512])
#define SB(T, Q) gload_lds16(pBq[Q] + (T) * 64, \
        &LDSU[(((T) & 1) << 15) + 16384 + ((Q) * 8 + dsub) * 512])

    bf16x8 aq[2][4], bn0[2][2], bn1[2][2];

#define RDA(MH) \
    _Pragma("unroll") for (int ks = 0; ks < 2; ++ks) \
    _Pragma("unroll") for (int mi = 0; mi < 4; ++mi) \
        aq[ks][mi] = *(const bf16x8*)(buf + ((wr * 8 + (MH) * 4 + mi) * 2 + ks) * 512 + rdo)
#define RDB(NH, BN) \
    _Pragma("unroll") for (int ks = 0; ks < 2; ++ks) \
    _Pragma("unroll") for (int ni = 0; ni < 2; ++ni) \
        BN[ks][ni] = *(const bf16x8*)(buf + 16384 + ((wc * 4 + (NH) * 2 + ni) * 2 + ks) * 512 + rdo)
#define MMQ(MH, NH, BN) \
    __builtin_amdgcn_s_setprio(1); \
    _Pragma("unroll") for (int ks = 0; ks < 2; ++ks) \
    _Pragma("unroll") for (int mi = 0; mi < 4; ++mi) \
    _Pragma("unroll") for (int ni = 0; ni < 2; ++ni) \
        acc[(MH) * 4 + mi][(NH) * 2 + ni] = __builtin_amdgcn_mfma_f32_16x16x32_bf16( \
            aq[ks][mi], BN[ks][ni], acc[(MH) * 4 + mi][(NH) * 2 + ni], 0, 0, 0); \
    __builtin_amdgcn_s_setprio(0)

    // prologue: stage tile 0 in the steady-state order, confirm first 6
    SA(0, 0); SA(0, 2); SB(0, 0); SB(0, 1); SB(0, 2); SB(0, 3); SA(0, 1); SA(0, 3);
    VMW(2); BAR();

    for (int t = 0; t < 16; ++t) {
        const unsigned short* buf = &LDSU[(t & 1) << 15];
        // ---- ph1: Q(0,0); stage A q0,q2 of t+1 ----
        RDA(0);
        RDB(0, bn0);
        if (t < 15) { SA(t + 1, 0); SA(t + 1, 2); }
        BAR(); LGKM0();
        MMQ(0, 0, bn0);
        BAR();
        // ---- ph2: Q(0,1); stage B q0,q1 of t+1; confirm A q1,q3 of t ----
        RDB(1, bn1);
        if (t < 15) { SB(t + 1, 0); SB(t + 1, 1); }
        BAR(); LGKM0();
        MMQ(0, 1, bn1);
        if (t < 15) { VMW(4); } else { VMW(0); }
        BAR();
        // ---- ph3: Q(1,1); stage B q2,q3 of t+1 ----
        RDA(1);
        if (t < 15) { SB(t + 1, 2); SB(t + 1, 3); }
        BAR(); LGKM0();
        MMQ(1, 1, bn1);
        BAR();
        // ---- ph4: Q(1,0); stage A q1,q3 of t+1; confirm t+1's first 6 ----
        if (t < 15) { SA(t + 1, 1); SA(t + 1, 3); }
        MMQ(1, 0, bn0);
        if (t < 15) { VMW(2); }
        BAR();
    }

    // ---- epilogue: act -> f16 via LDS, then coalesced 16B global stores ----
    _Float16* T = (_Float16*)LDSU;   // [256][256] f16, col ^ ((row>>2&3)<<4)
#pragma unroll
    for (int ni = 0; ni < 4; ++ni) {
        int col = wc * 64 + ni * 16 + lr;
        int gcol = n0 + col;
        bool is_g = ((gcol >> 10) == 2);
        float bv = bias[gcol];
#pragma unroll
        for (int mi = 0; mi < 8; ++mi) {
#pragma unroll
            for (int r = 0; r < 4; ++r) {
                int row = wr * 128 + mi * 16 + lg * 4 + r;
                float v = acc[mi][ni][r] + bv;
                float e;
                if (is_g) e = 1.f - 2.f / (1.f + __expf(2.f * v));   // tanh
                else      e = 1.f / (1.f + __expf(-v));              // sigmoid
                T[row * 256 + (col ^ (((row >> 2) & 3) << 4))] = (_Float16)e;
            }
        }
    }
    BAR();
#pragma unroll
    for (int p = 0; p < 16; ++p) {
        int q = p * 512 + tid;           // 16B-slot id, 0..8191
        int row = q >> 5, s = q & 31;
        int cs = (s * 8) ^ (((row >> 2) & 3) << 4);
        uint4 val = *(const uint4*)(T + row * 256 + cs);
        *(uint4*)(gates + (size_t)(m0 + row) * FOURH + n0 + s * 8) = val;
    }
#undef SA
#undef SB
#undef RDA
#undef RDB
#undef MMQ
}

// ---------- kernel 4: recurrence, burst-8 prefetch, one thread per (b,h) ------
__global__ __launch_bounds__(256) void lstm_recur(
    const _Float16* __restrict__ gates,  // [64*chunk][4096] activated f16
    float* __restrict__ out,             // d_out base (f32)
    float* __restrict__ cstate,          // [65536]
    int chunk, int s0) {
    int t = blockIdx.x * 256 + threadIdx.x;  // 0..65535
    int b = t >> 10, h = t & 1023;
    float c = (s0 == 0) ? 0.f : cstate[t];
    const _Float16* gp = gates + (size_t)b * chunk * FOURH + h;
    float* op = out + (size_t)(b * SEQ + s0) * HS + h;
    float hv = 0.f;
    for (int sl = 0; sl < chunk; sl += 8) {
        float iv[8], fv[8], gv[8], ov[8];
#pragma unroll
        for (int u = 0; u < 8; ++u) {
            const _Float16* q = gp + (size_t)(sl + u) * FOURH;
            iv[u] = (float)q[0];
            fv[u] = (float)q[1024];
            gv[u] = (float)q[2048];
            ov[u] = (float)q[3072];
        }
#pragma unroll
        for (int u = 0; u < 8; ++u) {
            c = fv[u] * c + iv[u] * gv[u];
            float th = 1.f - 2.f / (1.f + __expf(2.f * c));
            hv = ov[u] * th;
            op[(size_t)(sl + u) * HS] = hv;
        }
    }
    cstate[t] = c;
    if (s0 + chunk == SEQ) {
        out[(size_t)BATCH * SEQ * HS + t] = hv;                      // h_T
        out[(size_t)BATCH * SEQ * HS + BATCH * HS + t] = c;          // c_T
    }
}

// ---------- launcher ----------
extern "C" void kernel_launch(void* const* d_in, const int* in_sizes, int n_in,
                              void* d_out, int out_size, void* d_ws, size_t ws_size,
                              hipStream_t stream) {
    const float* x    = (const float*)d_in[0];
    const float* U    = (const float*)d_in[1];
    const float* bias = (const float*)d_in[2];
    float* out = (float*)d_out;
    char*  ws  = (char*)d_ws;

    // ws layout
    unsigned short* Xb = (unsigned short*)ws;                   // 64MB  bf16 x
    unsigned short* Ut = (unsigned short*)(ws + 67108864);      // 8MB   bf16 U^T
    float* cstate      = (float*)(ws + 75497472);               // 256KB
    _Float16* gates    = (_Float16*)(ws + 75759616);            // chunk*0.5MB
    const size_t fixed = 75759616;

    int chunk = 512;
    while (chunk > 4 && fixed + (size_t)BATCH * chunk * FOURH * 2 > ws_size)
        chunk >>= 1;
    int lg2 = 31 - __builtin_clz(chunk);

    convert_x<<<2048, 256, 0, stream>>>(x, Xb, (long)BATCH * SEQ * HS / 8);
    transpose_u<<<4096, 256, 0, stream>>>(U, Ut);

    for (int s0 = 0; s0 < SEQ; s0 += chunk) {
        int mtiles = (BATCH * chunk) / 256;
        gemm_gates8<<<mtiles * 16, 512, 0, stream>>>(Xb, Ut, bias, gates, lg2, s0);
        lstm_recur<<<256, 256, 0, stream>>>(gates, out, cstate, chunk, s0);
    }
}

// Round 7
// 454.484 us; speedup vs baseline: 1.3219x; 1.0089x over previous
//
#include <hip/hip_runtime.h>
#include <hip/hip_bf16.h>
#include <stdint.h>

// ---------- types ----------
typedef __bf16 bf16x8 __attribute__((ext_vector_type(8)));
typedef float  f32x4  __attribute__((ext_vector_type(4)));
typedef unsigned short u16x8 __attribute__((ext_vector_type(8)));

#define HS    1024     // hidden size
#define FOURH 4096
#define SEQ   512
#define BATCH 64

#define BAR()  asm volatile("s_barrier" ::: "memory")
#define VMW(n) asm volatile("s_waitcnt vmcnt(" #n ")" ::: "memory")

// manual round-to-nearest-even f32 -> bf16 bits
__device__ __forceinline__ unsigned short f2bf(float f) {
    unsigned u = __builtin_bit_cast(unsigned, f);
    u = (u + 0x7FFFu + ((u >> 16) & 1u)) >> 16;
    return (unsigned short)u;
}

__device__ __forceinline__ void gload_lds16(const void* g, void* l) {
    __builtin_amdgcn_global_load_lds(
        (const __attribute__((address_space(1))) void*)g,
        (__attribute__((address_space(3))) void*)l, 16, 0, 0);
}

// ---------- kernel 1: x (f32) -> Xb (bf16) ----------
__global__ __launch_bounds__(256) void convert_x(const float* __restrict__ x,
                                                 unsigned short* __restrict__ xb,
                                                 long n8) {
    long i = (long)blockIdx.x * blockDim.x + threadIdx.x;
    long stride = (long)gridDim.x * blockDim.x;
    for (; i < n8; i += stride) {
        const float4* p = (const float4*)(x + i * 8);
        float4 a = p[0], b = p[1];
        u16x8 o;
        o[0] = f2bf(a.x); o[1] = f2bf(a.y); o[2] = f2bf(a.z); o[3] = f2bf(a.w);
        o[4] = f2bf(b.x); o[5] = f2bf(b.y); o[6] = f2bf(b.z); o[7] = f2bf(b.w);
        *(u16x8*)(xb + i * 8) = o;
    }
}

// ---------- kernel 2: U [1024][4096] f32 -> Ut [4096][1024] bf16 ----------
__global__ __launch_bounds__(256) void transpose_u(const float* __restrict__ U,
                                                   unsigned short* __restrict__ Ut) {
    __shared__ float tile[32][33];
    int bx = blockIdx.x;            // 4096 blocks
    int tn = bx >> 5;               // n tile
    int tk = bx & 31;               // k tile
    int c = threadIdx.x & 31;
    int r = threadIdx.x >> 5;
#pragma unroll
    for (int i = 0; i < 4; ++i) {
        int k = tk * 32 + r + i * 8;
        tile[r + i * 8][c] = U[(size_t)k * FOURH + tn * 32 + c];
    }
    __syncthreads();
#pragma unroll
    for (int i = 0; i < 4; ++i) {
        int nl = r + i * 8;
        Ut[(size_t)(tn * 32 + nl) * HS + tk * 32 + c] = f2bf(tile[c][nl]);
    }
}

// ---------- kernel 3: 256x256, BK=64 GEMM, 2 barriers/tile, counted vmcnt ----
// 8 waves (2M x 4N). Tile regions: R1 = Q(0,0)+Q(0,1), R2 = Q(1,1)+Q(1,0).
// Stage order of t+1: {A02 | B01} in R1, {B23 | A13} in R2. VMW(4)+BAR mid-
// tile (confirms A13 of t), VMW(2)+BAR at boundary (confirms first 6 of t+1).
// Queue oscillates 2..8 outstanding; never drains in steady state.
__global__ __launch_bounds__(512, 1) void gemm_gates8(
    const unsigned short* __restrict__ Xb,   // [B*S][1024] bf16
    const unsigned short* __restrict__ Ut,   // [4096][1024] bf16
    const float* __restrict__ bias,          // [4096]
    _Float16* __restrict__ gates,            // [BATCH*chunk][4096] activated f16
    int lg2chunk, int s0) {
    __shared__ unsigned short LDSU[65536];   // 128KB: buf(t&1)*32768; A@0, B@+16384

    // T1: XCD-aware block swizzle (nwg multiple of 8)
    int nwg = gridDim.x;
    int bid = blockIdx.x;
    int wg = (bid & 7) * (nwg >> 3) + (bid >> 3);
    int mt = wg >> 4;            // 16 n-tiles (4096/256)
    int nt = wg & 15;

    int tid = threadIdx.x;
    int w = tid >> 6, l = tid & 63;
    int wr = w >> 2, wc = w & 3;       // wave grid 2 (M) x 4 (N)
    int lr = l & 15, lg = l >> 4;

    const int m0 = mt * 256, n0 = nt * 256;
    const int cmask = (1 << lg2chunk) - 1;

    // ds_read offset within a 16x32 subtile (ushort units), st_16x32 swizzle
    const int rdo = lr * 32 + ((lg * 8) ^ ((lr & 8) << 1));

    // staging lane geometry: lane covers row l>>2 of its subtile, k-octet (l&3)
    const int srow = l >> 2;
    const int skin = ((l & 3) * 8) ^ (((l >> 5) & 1) << 4);

    // per-quarter global source pointers (quarter q = 64 rows; wave w covers
    // subtile rs = q*4 + (w>>1), kc = w&1)
    const unsigned short* pAq[4];
    const unsigned short* pBq[4];
#pragma unroll
    for (int q = 0; q < 4; ++q) {
        int rowg = q * 64 + (w >> 1) * 16 + srow;
        int mrow = m0 + rowg;
        int b = mrow >> lg2chunk, sl2 = mrow & cmask;
        pAq[q] = Xb + (size_t)(b * SEQ + s0 + sl2) * HS + (w & 1) * 32 + skin;
        pBq[q] = Ut + (size_t)(n0 + rowg) * HS + (w & 1) * 32 + skin;
    }
    const int dsub = (w >> 1) * 2 + (w & 1);   // subtile slot within quarter

    f32x4 acc[8][4];
#pragma unroll
    for (int mi = 0; mi < 8; ++mi)
#pragma unroll
        for (int ni = 0; ni < 4; ++ni) acc[mi][ni] = 0.f;

#define SA(T, Q) gload_lds16(pAq[Q] + (T) * 64, \
        &LDSU[(((T) & 1) << 15) + ((Q) * 8 + dsub) * 512])
#define SB(T, Q) gload_lds16(pBq[Q] + (T) * 64, \
        &LDSU[(((T) & 1) << 15) + 16384 + ((Q) * 8 + dsub) * 512])

    bf16x8 aq[2][4], bn0[2][2], bn1[2][2];

#define RDA(MH) \
    _Pragma("unroll") for (int ks = 0; ks < 2; ++ks) \
    _Pragma("unroll") for (int mi = 0; mi < 4; ++mi) \
        aq[ks][mi] = *(const bf16x8*)(buf + ((wr * 8 + (MH) * 4 + mi) * 2 + ks) * 512 + rdo)
#define RDB(NH, BN) \
    _Pragma("unroll") for (int ks = 0; ks < 2; ++ks) \
    _Pragma("unroll") for (int ni = 0; ni < 2; ++ni) \
        BN[ks][ni] = *(const bf16x8*)(buf + 16384 + ((wc * 4 + (NH) * 2 + ni) * 2 + ks) * 512 + rdo)
#define MMQ(MH, NH, BN) \
    __builtin_amdgcn_s_setprio(1); \
    _Pragma("unroll") for (int ks = 0; ks < 2; ++ks) \
    _Pragma("unroll") for (int mi = 0; mi < 4; ++mi) \
    _Pragma("unroll") for (int ni = 0; ni < 2; ++ni) \
        acc[(MH) * 4 + mi][(NH) * 2 + ni] = __builtin_amdgcn_mfma_f32_16x16x32_bf16( \
            aq[ks][mi], BN[ks][ni], acc[(MH) * 4 + mi][(NH) * 2 + ni], 0, 0, 0); \
    __builtin_amdgcn_s_setprio(0)

    // prologue: stage tile 0 in steady-state order, confirm first 6
    SA(0, 0); SA(0, 2); SB(0, 0); SB(0, 1); SB(0, 2); SB(0, 3); SA(0, 1); SA(0, 3);
    VMW(2); BAR();

    for (int t = 0; t < 16; ++t) {
        const unsigned short* buf = &LDSU[(t & 1) << 15];
        // ---- region 1: Q(0,0) + Q(0,1); stage A02, B01 of t+1 ----
        RDA(0);
        RDB(0, bn0);
        if (t < 15) { SA(t + 1, 0); SA(t + 1, 2); }
        MMQ(0, 0, bn0);
        RDB(1, bn1);
        if (t < 15) { SB(t + 1, 0); SB(t + 1, 1); }
        MMQ(0, 1, bn1);
        if (t < 15) { VMW(4); } else { VMW(0); }
        BAR();
        // ---- region 2: Q(1,1) + Q(1,0); stage B23, A13 of t+1 ----
        RDA(1);
        if (t < 15) { SB(t + 1, 2); SB(t + 1, 3); }
        MMQ(1, 1, bn1);
        if (t < 15) { SA(t + 1, 1); SA(t + 1, 3); }
        MMQ(1, 0, bn0);
        if (t < 15) { VMW(2); }
        BAR();
    }

    // ---- epilogue: act -> f16 via LDS, then coalesced 16B global stores ----
    _Float16* T = (_Float16*)LDSU;   // [256][256] f16, col ^ ((row>>2&3)<<4)
#pragma unroll
    for (int ni = 0; ni < 4; ++ni) {
        int col = wc * 64 + ni * 16 + lr;
        int gcol = n0 + col;
        bool is_g = ((gcol >> 10) == 2);
        float bv = bias[gcol];
#pragma unroll
        for (int mi = 0; mi < 8; ++mi) {
#pragma unroll
            for (int r = 0; r < 4; ++r) {
                int row = wr * 128 + mi * 16 + lg * 4 + r;
                float v = acc[mi][ni][r] + bv;
                float e;
                if (is_g) e = 1.f - 2.f / (1.f + __expf(2.f * v));   // tanh
                else      e = 1.f / (1.f + __expf(-v));              // sigmoid
                T[row * 256 + (col ^ (((row >> 2) & 3) << 4))] = (_Float16)e;
            }
        }
    }
    BAR();
#pragma unroll
    for (int p = 0; p < 16; ++p) {
        int q = p * 512 + tid;           // 16B-slot id, 0..8191
        int row = q >> 5, s = q & 31;
        int cs = (s * 8) ^ (((row >> 2) & 3) << 4);
        uint4 val = *(const uint4*)(T + row * 256 + cs);
        *(uint4*)(gates + (size_t)(m0 + row) * FOURH + n0 + s * 8) = val;
    }
#undef SA
#undef SB
#undef RDA
#undef RDB
#undef MMQ
}

// ---------- kernel 4: recurrence, burst-8 prefetch, one thread per (b,h) ------
__global__ __launch_bounds__(256) void lstm_recur(
    const _Float16* __restrict__ gates,  // [64*chunk][4096] activated f16
    float* __restrict__ out,             // d_out base (f32)
    float* __restrict__ cstate,          // [65536]
    int chunk, int s0) {
    int t = blockIdx.x * 256 + threadIdx.x;  // 0..65535
    int b = t >> 10, h = t & 1023;
    float c = (s0 == 0) ? 0.f : cstate[t];
    const _Float16* gp = gates + (size_t)b * chunk * FOURH + h;
    float* op = out + (size_t)(b * SEQ + s0) * HS + h;
    float hv = 0.f;
    for (int sl = 0; sl < chunk; sl += 8) {
        float iv[8], fv[8], gv[8], ov[8];
#pragma unroll
        for (int u = 0; u < 8; ++u) {
            const _Float16* q = gp + (size_t)(sl + u) * FOURH;
            iv[u] = (float)q[0];
            fv[u] = (float)q[1024];
            gv[u] = (float)q[2048];
            ov[u] = (float)q[3072];
        }
#pragma unroll
        for (int u = 0; u < 8; ++u) {
            c = fv[u] * c + iv[u] * gv[u];
            float th = 1.f - 2.f / (1.f + __expf(2.f * c));
            hv = ov[u] * th;
            op[(size_t)(sl + u) * HS] = hv;
        }
    }
    cstate[t] = c;
    if (s0 + chunk == SEQ) {
        out[(size_t)BATCH * SEQ * HS + t] = hv;                      // h_T
        out[(size_t)BATCH * SEQ * HS + BATCH * HS + t] = c;          // c_T
    }
}

// ---------- launcher ----------
extern "C" void kernel_launch(void* const* d_in, const int* in_sizes, int n_in,
                              void* d_out, int out_size, void* d_ws, size_t ws_size,
                              hipStream_t stream) {
    const float* x    = (const float*)d_in[0];
    const float* U    = (const float*)d_in[1];
    const float* bias = (const float*)d_in[2];
    float* out = (float*)d_out;
    char*  ws  = (char*)d_ws;

    // ws layout
    unsigned short* Xb = (unsigned short*)ws;                   // 64MB  bf16 x
    unsigned short* Ut = (unsigned short*)(ws + 67108864);      // 8MB   bf16 U^T
    float* cstate      = (float*)(ws + 75497472);               // 256KB
    _Float16* gates    = (_Float16*)(ws + 75759616);            // chunk*0.5MB
    const size_t fixed = 75759616;

    int chunk = 512;
    while (chunk > 4 && fixed + (size_t)BATCH * chunk * FOURH * 2 > ws_size)
        chunk >>= 1;
    int lg2 = 31 - __builtin_clz(chunk);

    convert_x<<<2048, 256, 0, stream>>>(x, Xb, (long)BATCH * SEQ * HS / 8);
    transpose_u<<<4096, 256, 0, stream>>>(U, Ut);

    for (int s0 = 0; s0 < SEQ; s0 += chunk) {
        int mtiles = (BATCH * chunk) / 256;
        gemm_gates8<<<mtiles * 16, 512, 0, stream>>>(Xb, Ut, bias, gates, lg2, s0);
        lstm_recur<<<256, 256, 0, stream>>>(gates, out, cstate, chunk, s0);
    }
}

// Round 8
// 399.818 us; speedup vs baseline: 1.5027x; 1.1367x over previous
//
#include <hip/hip_runtime.h>
#include <hip/hip_bf16.h>
#include <stdint.h>

// ---------- types ----------
typedef __bf16 bf16x8 __attribute__((ext_vector_type(8)));
typedef float  f32x4  __attribute__((ext_vector_type(4)));
typedef unsigned short u16x8 __attribute__((ext_vector_type(8)));
typedef unsigned short u16x4 __attribute__((ext_vector_type(4)));
typedef _Float16 f16x4 __attribute__((ext_vector_type(4)));

#define HS    1024     // hidden size
#define FOURH 4096
#define SEQ   512
#define BATCH 64

#define BAR()  asm volatile("s_barrier" ::: "memory")
#define VMW(n) asm volatile("s_waitcnt vmcnt(" #n ")" ::: "memory")

// manual round-to-nearest-even f32 -> bf16 bits
__device__ __forceinline__ unsigned short f2bf(float f) {
    unsigned u = __builtin_bit_cast(unsigned, f);
    u = (u + 0x7FFFu + ((u >> 16) & 1u)) >> 16;
    return (unsigned short)u;
}

__device__ __forceinline__ void gload_lds16(const void* g, void* l) {
    __builtin_amdgcn_global_load_lds(
        (const __attribute__((address_space(1))) void*)g,
        (__attribute__((address_space(3))) void*)l, 16, 0, 0);
}

__device__ __forceinline__ float fsigmoid(float v) {
    return __builtin_amdgcn_rcpf(1.f + __expf(-v));
}
__device__ __forceinline__ float ftanh(float v) {
    return 1.f - 2.f * __builtin_amdgcn_rcpf(1.f + __expf(2.f * v));
}

// ---------- kernel 1: x (f32) -> Xb (bf16) ----------
__global__ __launch_bounds__(256) void convert_x(const float* __restrict__ x,
                                                 unsigned short* __restrict__ xb,
                                                 long n8) {
    long i = (long)blockIdx.x * blockDim.x + threadIdx.x;
    long stride = (long)gridDim.x * blockDim.x;
    for (; i < n8; i += stride) {
        const float4* p = (const float4*)(x + i * 8);
        float4 a = p[0], b = p[1];
        u16x8 o;
        o[0] = f2bf(a.x); o[1] = f2bf(a.y); o[2] = f2bf(a.z); o[3] = f2bf(a.w);
        o[4] = f2bf(b.x); o[5] = f2bf(b.y); o[6] = f2bf(b.z); o[7] = f2bf(b.w);
        *(u16x8*)(xb + i * 8) = o;
    }
}

// ---------- kernel 2: U [1024][4096] f32 -> Ut [4096][1024] bf16 ----------
__global__ __launch_bounds__(256) void transpose_u(const float* __restrict__ U,
                                                   unsigned short* __restrict__ Ut) {
    __shared__ float tile[32][33];
    int bx = blockIdx.x;            // 4096 blocks
    int tn = bx >> 5;               // n tile
    int tk = bx & 31;               // k tile
    int c = threadIdx.x & 31;
    int r = threadIdx.x >> 5;
#pragma unroll
    for (int i = 0; i < 4; ++i) {
        int k = tk * 32 + r + i * 8;
        tile[r + i * 8][c] = U[(size_t)k * FOURH + tn * 32 + c];
    }
    __syncthreads();
#pragma unroll
    for (int i = 0; i < 4; ++i) {
        int nl = r + i * 8;
        Ut[(size_t)(tn * 32 + nl) * HS + tk * 32 + c] = f2bf(tile[c][nl]);
    }
}

// ---------- kernel 3: 256x256, BK=64 GEMM, 2 barriers/tile, counted vmcnt ----
// 8 waves (2M x 4N). Same proven r7 core. Epilogue: bias+act then DIRECT
// packed f16x4 stores into G[row/4][4096][4] (4 consecutive timesteps of one
// (gate,h) per 8B store; lanes form 512B contiguous segments).
__global__ __launch_bounds__(512, 1) void gemm_gates8(
    const unsigned short* __restrict__ Xb,   // [B*S][1024] bf16
    const unsigned short* __restrict__ Ut,   // [4096][1024] bf16
    const float* __restrict__ bias,          // [4096]
    _Float16* __restrict__ gates,            // packed [BATCH*chunk/4][4096][4]
    int lg2chunk, int s0) {
    __shared__ unsigned short LDSU[65536];   // 128KB: buf(t&1)*32768; A@0, B@+16384

    // T1: XCD-aware block swizzle (nwg multiple of 8)
    int nwg = gridDim.x;
    int bid = blockIdx.x;
    int wg = (bid & 7) * (nwg >> 3) + (bid >> 3);
    int mt = wg >> 4;            // 16 n-tiles (4096/256)
    int nt = wg & 15;

    int tid = threadIdx.x;
    int w = tid >> 6, l = tid & 63;
    int wr = w >> 2, wc = w & 3;       // wave grid 2 (M) x 4 (N)
    int lr = l & 15, lg = l >> 4;

    const int m0 = mt * 256, n0 = nt * 256;
    const int cmask = (1 << lg2chunk) - 1;

    // ds_read offset within a 16x32 subtile (ushort units), st_16x32 swizzle
    const int rdo = lr * 32 + ((lg * 8) ^ ((lr & 8) << 1));

    // staging lane geometry: lane covers row l>>2 of its subtile, k-octet (l&3)
    const int srow = l >> 2;
    const int skin = ((l & 3) * 8) ^ (((l >> 5) & 1) << 4);

    // per-quarter global source pointers (quarter q = 64 rows; wave w covers
    // subtile rs = q*4 + (w>>1), kc = w&1)
    const unsigned short* pAq[4];
    const unsigned short* pBq[4];
#pragma unroll
    for (int q = 0; q < 4; ++q) {
        int rowg = q * 64 + (w >> 1) * 16 + srow;
        int mrow = m0 + rowg;
        int b = mrow >> lg2chunk, sl2 = mrow & cmask;
        pAq[q] = Xb + (size_t)(b * SEQ + s0 + sl2) * HS + (w & 1) * 32 + skin;
        pBq[q] = Ut + (size_t)(n0 + rowg) * HS + (w & 1) * 32 + skin;
    }
    const int dsub = (w >> 1) * 2 + (w & 1);   // subtile slot within quarter

    f32x4 acc[8][4];
#pragma unroll
    for (int mi = 0; mi < 8; ++mi)
#pragma unroll
        for (int ni = 0; ni < 4; ++ni) acc[mi][ni] = 0.f;

#define SA(T, Q) gload_lds16(pAq[Q] + (T) * 64, \
        &LDSU[(((T) & 1) << 15) + ((Q) * 8 + dsub) * 512])
#define SB(T, Q) gload_lds16(pBq[Q] + (T) * 64, \
        &LDSU[(((T) & 1) << 15) + 16384 + ((Q) * 8 + dsub) * 512])

    bf16x8 aq[2][4], bn0[2][2], bn1[2][2];

#define RDA(MH) \
    _Pragma("unroll") for (int ks = 0; ks < 2; ++ks) \
    _Pragma("unroll") for (int mi = 0; mi < 4; ++mi) \
        aq[ks][mi] = *(const bf16x8*)(buf + ((wr * 8 + (MH) * 4 + mi) * 2 + ks) * 512 + rdo)
#define RDB(NH, BN) \
    _Pragma("unroll") for (int ks = 0; ks < 2; ++ks) \
    _Pragma("unroll") for (int ni = 0; ni < 2; ++ni) \
        BN[ks][ni] = *(const bf16x8*)(buf + 16384 + ((wc * 4 + (NH) * 2 + ni) * 2 + ks) * 512 + rdo)
#define MMQ(MH, NH, BN) \
    __builtin_amdgcn_s_setprio(1); \
    _Pragma("unroll") for (int ks = 0; ks < 2; ++ks) \
    _Pragma("unroll") for (int mi = 0; mi < 4; ++mi) \
    _Pragma("unroll") for (int ni = 0; ni < 2; ++ni) \
        acc[(MH) * 4 + mi][(NH) * 2 + ni] = __builtin_amdgcn_mfma_f32_16x16x32_bf16( \
            aq[ks][mi], BN[ks][ni], acc[(MH) * 4 + mi][(NH) * 2 + ni], 0, 0, 0); \
    __builtin_amdgcn_s_setprio(0)

    // prologue: stage tile 0 in steady-state order, confirm first 6
    SA(0, 0); SA(0, 2); SB(0, 0); SB(0, 1); SB(0, 2); SB(0, 3); SA(0, 1); SA(0, 3);
    VMW(2); BAR();

    for (int t = 0; t < 16; ++t) {
        const unsigned short* buf = &LDSU[(t & 1) << 15];
        // ---- region 1: Q(0,0) + Q(0,1); stage A02, B01 of t+1 ----
        RDA(0);
        RDB(0, bn0);
        if (t < 15) { SA(t + 1, 0); SA(t + 1, 2); }
        MMQ(0, 0, bn0);
        RDB(1, bn1);
        if (t < 15) { SB(t + 1, 0); SB(t + 1, 1); }
        MMQ(0, 1, bn1);
        if (t < 15) { VMW(4); } else { VMW(0); }
        BAR();
        // ---- region 2: Q(1,1) + Q(1,0); stage B23, A13 of t+1 ----
        RDA(1);
        if (t < 15) { SB(t + 1, 2); SB(t + 1, 3); }
        MMQ(1, 1, bn1);
        if (t < 15) { SA(t + 1, 1); SA(t + 1, 3); }
        MMQ(1, 0, bn0);
        if (t < 15) { VMW(2); }
        BAR();
    }

    // ---- epilogue: bias + act, direct packed f16x4 stores ----
    // C/D map: col = lane&15, row = (lane>>4)*4 + r  ->  the 4 r-values are
    // 4 consecutive M-rows (timesteps). Pack to one 8B store per (mi,ni).
#pragma unroll
    for (int ni = 0; ni < 4; ++ni) {
        int gcol = n0 + wc * 64 + ni * 16 + lr;
        bool is_g = ((gcol >> 10) == 2);
        float bv = bias[gcol];
#pragma unroll
        for (int mi = 0; mi < 8; ++mi) {
            int rg = ((m0 + wr * 128 + mi * 16) >> 2) + lg;   // row-group
            u16x4 pk;
#pragma unroll
            for (int r = 0; r < 4; ++r) {
                float v = acc[mi][ni][r] + bv;
                float e = is_g ? ftanh(v) : fsigmoid(v);
                pk[r] = __builtin_bit_cast(unsigned short, (_Float16)e);
            }
            *(u16x4*)(gates + ((size_t)rg * FOURH + gcol) * 4) = pk;
        }
    }
#undef SA
#undef SB
#undef RDA
#undef RDB
#undef MMQ
}

// ---------- kernel 4: recurrence on packed gates, one thread per (b,h) -------
__global__ __launch_bounds__(256) void lstm_recur(
    const _Float16* __restrict__ gates,  // packed [rows/4][4096][4] activated
    float* __restrict__ out,             // d_out base (f32)
    float* __restrict__ cstate,          // [65536]
    int chunk, int s0) {
    int t = blockIdx.x * 256 + threadIdx.x;  // 0..65535
    int b = t >> 10, h = t & 1023;
    float c = (s0 == 0) ? 0.f : cstate[t];
    const _Float16* gp = gates + ((size_t)((b * chunk) >> 2) * FOURH + h) * 4;
    float* op = out + (size_t)(b * SEQ + s0) * HS + h;
    float hv = 0.f;
    const int ng = chunk >> 2;               // row-groups of 4 steps
    for (int g4 = 0; g4 < ng; g4 += 2) {
        f16x4 iv[2], fv[2], gv[2], ov[2];
#pragma unroll
        for (int u = 0; u < 2; ++u) {
            const _Float16* q = gp + (size_t)(g4 + u) * (FOURH * 4);
            iv[u] = *(const f16x4*)(q);
            fv[u] = *(const f16x4*)(q + 4096);
            gv[u] = *(const f16x4*)(q + 8192);
            ov[u] = *(const f16x4*)(q + 12288);
        }
#pragma unroll
        for (int u = 0; u < 2; ++u) {
#pragma unroll
            for (int r = 0; r < 4; ++r) {
                c = (float)fv[u][r] * c + (float)iv[u][r] * (float)gv[u][r];
                float th = ftanh(c);
                hv = (float)ov[u][r] * th;
                op[(size_t)((g4 + u) * 4 + r) * HS] = hv;
            }
        }
    }
    cstate[t] = c;
    if (s0 + chunk == SEQ) {
        out[(size_t)BATCH * SEQ * HS + t] = hv;                      // h_T
        out[(size_t)BATCH * SEQ * HS + BATCH * HS + t] = c;          // c_T
    }
}

// ---------- launcher ----------
extern "C" void kernel_launch(void* const* d_in, const int* in_sizes, int n_in,
                              void* d_out, int out_size, void* d_ws, size_t ws_size,
                              hipStream_t stream) {
    const float* x    = (const float*)d_in[0];
    const float* U    = (const float*)d_in[1];
    const float* bias = (const float*)d_in[2];
    float* out = (float*)d_out;
    char*  ws  = (char*)d_ws;

    // ws layout
    unsigned short* Xb = (unsigned short*)ws;                   // 64MB  bf16 x
    unsigned short* Ut = (unsigned short*)(ws + 67108864);      // 8MB   bf16 U^T
    float* cstate      = (float*)(ws + 75497472);               // 256KB
    _Float16* gates    = (_Float16*)(ws + 75759616);            // chunk*0.5MB
    const size_t fixed = 75759616;

    int chunk = 512;
    while (chunk > 4 && fixed + (size_t)BATCH * chunk * FOURH * 2 > ws_size)
        chunk >>= 1;
    int lg2 = 31 - __builtin_clz(chunk);

    convert_x<<<2048, 256, 0, stream>>>(x, Xb, (long)BATCH * SEQ * HS / 8);
    transpose_u<<<4096, 256, 0, stream>>>(U, Ut);

    for (int s0 = 0; s0 < SEQ; s0 += chunk) {
        int mtiles = (BATCH * chunk) / 256;
        gemm_gates8<<<mtiles * 16, 512, 0, stream>>>(Xb, Ut, bias, gates, lg2, s0);
        lstm_recur<<<256, 256, 0, stream>>>(gates, out, cstate, chunk, s0);
    }
}